// Round 3
// baseline (507.138 us; speedup 1.0000x reference)
//
#include <hip/hip_runtime.h>
#include <hip/hip_bf16.h>

#define HH 100
#define WW 352
#define NB 2
#define LL 5
#define NN 10
#define CCH 64
#define HW (HH*WW)
#define KTOP (HW/4)
#define HP (HH+6)
#define WP 390   // 6*64 + 6, covers conv reads for padded W tiles

typedef __bf16 bf16x8 __attribute__((ext_vector_type(8)));
typedef float f32x4 __attribute__((ext_vector_type(4)));

// ws layout (bytes) — all 16B aligned
#define WS_CONF  0u
#define WS_TAU   1408000u
#define WS_SELP  1408064u
#define WS_SELK  1408128u
#define WS_WTP   1408192u
#define WS_PAD   1809600u
#define WS_GHIST 12392640u
#define PAD_BYTES   ((size_t)NB*HP*WP*CCH*2)     // 10,583,040
#define GHIST_BYTES ((size_t)NN*65536*4)          // 2,621,440

__device__ __forceinline__ void load_theta(const float* __restrict__ ptm, int b, int l, float th[6]) {
#pragma clang fp contract(off)
  const float* tb = ptm + ((b*LL + 0)*LL + l)*16;  // pairwise_t_matrix[b,0,l,:,:]
  th[0] = tb[0] * 1.0f;
  th[1] = tb[1] * (float)(100.0/352.0);
  th[2] = tb[3] * (float)(2.0/(2.0*0.4*352.0));
  th[3] = tb[4] * (float)(352.0/100.0);
  th[4] = tb[5] * 1.0f;
  th[5] = tb[7] * (float)(2.0/(2.0*0.4*100.0));
}

// --- Kernel 1: conf_w = bilinear-warp of sigmoid(max(psm)) + fused hi16 histogram ---
__global__ void conf_warp_kernel(const float* __restrict__ psm,
                                 const float* __restrict__ ptm,
                                 float* __restrict__ conf_w,
                                 unsigned int* __restrict__ ghist) {
#pragma clang fp contract(off)
  int w = blockIdx.x * 128 + threadIdx.x;
  int h = blockIdx.y;
  int n = blockIdx.z;
  if (w >= WW) return;
  int b = n / LL, l = n % LL;
  float th[6];
  load_theta(ptm, b, l, th);
  float gy = ((float)h + 0.5f) * (float)(2.0/100.0) - 1.0f;
  float gx = ((float)w + 0.5f) * (float)(2.0/352.0) - 1.0f;
  float sx = th[0]*gx + th[1]*gy + th[2];
  float sy = th[3]*gx + th[4]*gy + th[5];
  float px = (sx + 1.0f) * ((float)WW * 0.5f) - 0.5f;
  float py = (sy + 1.0f) * ((float)HH * 0.5f) - 0.5f;
  float x0 = floorf(px), y0 = floorf(py);
  float wx1 = px - x0, wx0 = 1.0f - wx1;
  float wy1 = py - y0, wy0 = 1.0f - wy1;
  const float* p0 = psm + (size_t)(n*2 + 0)*HW;
  const float* p1 = psm + (size_t)(n*2 + 1)*HW;
  float yy[2] = {y0, y0 + 1.0f};
  float xx[2] = {x0, x0 + 1.0f};
  float wgt[2][2] = {{wy0*wx0, wy0*wx1}, {wy1*wx0, wy1*wx1}};
  float out = 0.0f;
  for (int iy = 0; iy < 2; ++iy) {
    for (int ix = 0; ix < 2; ++ix) {
      float yv = yy[iy], xv = xx[ix];
      float yc = fminf(fmaxf(yv, 0.0f), (float)(HH-1));
      float xc = fminf(fmaxf(xv, 0.0f), (float)(WW-1));
      int yi = (int)yc, xi = (int)xc;
      int idx = yi*WW + xi;
      float m = fmaxf(p0[idx], p1[idx]);
      float v = 1.0f / (1.0f + expf(-m));
      bool valid = (yv >= 0.0f) && (yv <= (float)(HH-1)) && (xv >= 0.0f) && (xv <= (float)(WW-1));
      out += (valid ? v : 0.0f) * wgt[iy][ix];
    }
  }
  conf_w[(size_t)n*HW + h*WW + w] = out;
  // fused hi16 histogram: wave-aggregated global atomics (conf >= 0 -> bit order = float order)
  unsigned int bin = __float_as_uint(out) >> 16;
  int lane = threadIdx.x & 63;
  unsigned long long mask = __ballot(true);
  while (mask) {
    int srcl = (int)(__ffsll((long long)mask) - 1);
    unsigned int bsrc = (unsigned int)__shfl((int)bin, srcl);
    unsigned long long same = __ballot(bin == bsrc);
    if (lane == srcl)
      atomicAdd(&ghist[(size_t)n*65536 + bsrc], (unsigned int)__popcll(same & mask));
    mask &= ~same;
  }
}

// --- Kernel 2a: parallel select over 65536-bin hist (mode 0: hi16 + zero hist; mode 1: lo16 -> tau) ---
__global__ __launch_bounds__(256) void topk_select_kernel(unsigned int* __restrict__ ghist,
                                                          int* __restrict__ selp,
                                                          int* __restrict__ selk,
                                                          float* __restrict__ tau,
                                                          int mode) {
  __shared__ unsigned int wsum[4];
  int n = blockIdx.x;
  unsigned int* gh = ghist + (size_t)n*65536;
  int tid = threadIdx.x;
  int lane = tid & 63, wid = tid >> 6;
  int k = (mode == 0) ? KTOP : selk[n];
  int base = 65535 - tid*256;      // thread's chunk, walked descending
  unsigned int csum = 0;
  for (int i = 0; i < 256; ++i) csum += gh[base - i];
  unsigned int inc = csum;
  for (int off = 1; off < 64; off <<= 1) {
    unsigned int o = __shfl_up(inc, off);
    if (lane >= off) inc += o;
  }
  if (lane == 63) wsum[wid] = inc;
  __syncthreads();
  unsigned int wadd = 0;
  for (int w2 = 0; w2 < wid; ++w2) wadd += wsum[w2];
  unsigned int incl = inc + wadd;
  unsigned int excl = incl - csum;  // count of elements in strictly-higher bins
  if (excl < (unsigned int)k && incl >= (unsigned int)k) {
    unsigned int run = excl;
    for (int i = 0; i < 256; ++i) {
      unsigned int c = gh[base - i];
      if (run + c >= (unsigned int)k) {
        int bin = base - i;
        if (mode == 0) { selp[n] = bin; selk[n] = k - (int)run; }
        else tau[n] = __uint_as_float(((unsigned int)selp[n] << 16) | (unsigned int)bin);
        break;
      }
      run += c;
    }
  }
  if (mode == 0) {
    for (int i = 0; i < 256; ++i) gh[base - i] = 0u;  // re-zero for lo16 pass
  }
}

// --- Kernel 2b: conditional rescan — lo16 histogram among elements matching hi16 prefix ---
__global__ void scan_lo_kernel(const float* __restrict__ conf_w,
                               const int* __restrict__ selp,
                               unsigned int* __restrict__ ghist) {
  int n = blockIdx.y;
  unsigned int hi = (unsigned int)selp[n];
  const float4* src = (const float4*)(conf_w + (size_t)n*HW);
  unsigned int* gh = ghist + (size_t)n*65536;
  for (int i = blockIdx.x*256 + threadIdx.x; i < HW/4; i += 16*256) {
    float4 v = src[i];
    unsigned int u0 = __float_as_uint(v.x);
    unsigned int u1 = __float_as_uint(v.y);
    unsigned int u2 = __float_as_uint(v.z);
    unsigned int u3 = __float_as_uint(v.w);
    if ((u0 >> 16) == hi) atomicAdd(&gh[u0 & 0xFFFFu], 1u);
    if ((u1 >> 16) == hi) atomicAdd(&gh[u1 & 0xFFFFu], 1u);
    if ((u2 >> 16) == hi) atomicAdd(&gh[u2 & 0xFFFFu], 1u);
    if ((u3 >> 16) == hi) atomicAdd(&gh[u3 & 0xFFFFu], 1u);
  }
}

// --- Kernel 3: weights fuse_w[k][c][dy][dx] -> wtp[(dy*7+dx)*64 + k][c] bf16 ---
__global__ void pack_w_kernel(const float* __restrict__ fw, __bf16* __restrict__ wtp) {
  int idx = blockIdx.x*256 + threadIdx.x;
  if (idx >= CCH*CCH*49) return;
  int c = idx & 63;
  int k = (idx >> 6) & 63;
  int dydx = idx >> 12;
  wtp[((size_t)dydx*CCH + k)*CCH + c] = (__bf16)fw[((size_t)k*CCH + c)*49 + dydx];
}

// --- Kernel 4: fused warp + mask + mean over L, write bf16 NHWC into padded buffer ---
__global__ __launch_bounds__(256) void warp_avg_kernel(
    const float* __restrict__ x, const float* __restrict__ ptm,
    const float* __restrict__ conf_w, const float* __restrict__ tau,
    __bf16* __restrict__ pad) {
  int tx = threadIdx.x;     // w within tile, 0..63
  int cq = threadIdx.y;     // channel quarter, 0..3
  int w = blockIdx.x*64 + tx;
  int h = blockIdx.y;
  int b = blockIdx.z;
  if (w >= WW) return;      // halo stays zero from memset
  float acc[16];
#pragma unroll
  for (int i = 0; i < 16; ++i) acc[i] = 0.0f;
  float gy = ((float)h + 0.5f) * (float)(2.0/100.0) - 1.0f;
  float gx = ((float)w + 0.5f) * (float)(2.0/352.0) - 1.0f;
  for (int l = 0; l < LL; ++l) {
    int n = b*LL + l;
    float mk = 1.0f;
    if (l != 0)
      mk = (conf_w[(size_t)n*HW + h*WW + w] >= tau[n]) ? 1.0f : 0.0f;
    if (mk == 0.0f) continue;   // skip 4*16 loads when masked out
    float th[6];
    load_theta(ptm, b, l, th);
    float sx = th[0]*gx + th[1]*gy + th[2];
    float sy = th[3]*gx + th[4]*gy + th[5];
    float px = (sx + 1.0f) * ((float)WW*0.5f) - 0.5f;
    float py = (sy + 1.0f) * ((float)HH*0.5f) - 0.5f;
    float x0 = floorf(px), y0 = floorf(py);
    float wx1 = px - x0, wx0 = 1.0f - wx1;
    float wy1 = py - y0, wy0 = 1.0f - wy1;
    float y1 = y0 + 1.0f, x1 = x0 + 1.0f;
    bool vy0 = (y0 >= 0.0f) && (y0 <= (float)(HH-1));
    bool vy1 = (y1 >= 0.0f) && (y1 <= (float)(HH-1));
    bool vx0 = (x0 >= 0.0f) && (x0 <= (float)(WW-1));
    bool vx1 = (x1 >= 0.0f) && (x1 <= (float)(WW-1));
    int yi0 = (int)fminf(fmaxf(y0, 0.0f), (float)(HH-1));
    int yi1 = (int)fminf(fmaxf(y1, 0.0f), (float)(HH-1));
    int xi0 = (int)fminf(fmaxf(x0, 0.0f), (float)(WW-1));
    int xi1 = (int)fminf(fmaxf(x1, 0.0f), (float)(WW-1));
    float w00 = wy0*wx0 * ((vy0 && vx0) ? 1.0f : 0.0f);
    float w01 = wy0*wx1 * ((vy0 && vx1) ? 1.0f : 0.0f);
    float w10 = wy1*wx0 * ((vy1 && vx0) ? 1.0f : 0.0f);
    float w11 = wy1*wx1 * ((vy1 && vx1) ? 1.0f : 0.0f);
    int o00 = yi0*WW + xi0, o01 = yi0*WW + xi1;
    int o10 = yi1*WW + xi0, o11 = yi1*WW + xi1;
    const float* xb = x + ((size_t)n*CCH + cq*16)*HW;
#pragma unroll
    for (int c = 0; c < 16; ++c) {
      const float* xc = xb + (size_t)c*HW;
      acc[c] += xc[o00]*w00 + xc[o01]*w01 + xc[o10]*w10 + xc[o11]*w11;
    }
  }
  __bf16* dst = pad + (((size_t)b*HP + (h+3))*WP + (w+3))*CCH + cq*16;
#pragma unroll
  for (int c = 0; c < 16; ++c) dst[c] = (__bf16)(acc[c]*0.2f);
}

// --- Kernel 5: 7x7 conv, implicit GEMM with LDS-staged weights + pipelined B ---
// Block: 4 waves = 64 px x 4 rows x 32 kout. z = khalf*2 + b. Grid (6,25,4).
// Weights double-buffered in LDS (swizzled: chunk j stored at (j+row)%8).
__global__ __launch_bounds__(256, 3) void conv_kernel(
    const __bf16* __restrict__ pad, const __bf16* __restrict__ wtp,
    const float* __restrict__ fb, float* __restrict__ out) {
  __shared__ __align__(16) __bf16 wlds[2][32*64];
  int tid = threadIdx.x;
  int wave = tid >> 6, lane = tid & 63;
  int quad = lane >> 4, l16 = lane & 15;
  int z = blockIdx.z;
  int b = z & 1, khalf = z >> 1;
  int h = blockIdx.y*4 + wave;           // output row
  int w0 = blockIdx.x*64;
  // staging: thread t covers 16B: row sr, chunk sj, swizzled dest
  int sr = tid >> 3, sj = tid & 7;
  int sdst = sr*64 + ((sj + sr) & 7)*8;  // elements
  const __bf16* wsrc = wtp + khalf*2048 + tid*8;
  {
    bf16x8 v = *reinterpret_cast<const bf16x8*>(wsrc);
    *reinterpret_cast<bf16x8*>(&wlds[0][sdst]) = v;
  }
  // A-frag LDS offsets (elements): row = m*16+l16, chunk=(quad+4kc+row)%8
  int cj0 = (quad + l16) & 7;
  int cj1 = (quad + 4 + l16) & 7;
  int aoff00 = l16*64 + cj0*8,        aoff01 = l16*64 + cj1*8;
  int aoff10 = (l16+16)*64 + cj0*8,   aoff11 = (l16+16)*64 + cj1*8;
  f32x4 acc[2][4];
#pragma unroll
  for (int m = 0; m < 2; ++m)
#pragma unroll
    for (int n = 0; n < 4; ++n) acc[m][n] = (f32x4){0.f,0.f,0.f,0.f};
  const __bf16* prow = pad + (((size_t)b*HP + h)*WP + w0 + l16)*CCH + quad*8;
  bf16x8 bpre[4][2];
#pragma unroll
  for (int n = 0; n < 4; ++n)
#pragma unroll
    for (int kc = 0; kc < 2; ++kc)
      bpre[n][kc] = *reinterpret_cast<const bf16x8*>(prow + (n*16)*CCH + kc*32);
#pragma unroll 1
  for (int s = 0; s < 49; ++s) {
    __syncthreads();
    int cur = s & 1;
    bool has_next = (s + 1 < 49);
    bf16x8 wv;
    if (has_next) wv = *reinterpret_cast<const bf16x8*>(wsrc + (s+1)*4096);
    bf16x8 afr[2][2];
    afr[0][0] = *reinterpret_cast<const bf16x8*>(&wlds[cur][aoff00]);
    afr[0][1] = *reinterpret_cast<const bf16x8*>(&wlds[cur][aoff01]);
    afr[1][0] = *reinterpret_cast<const bf16x8*>(&wlds[cur][aoff10]);
    afr[1][1] = *reinterpret_cast<const bf16x8*>(&wlds[cur][aoff11]);
    bf16x8 bcur[4][2];
#pragma unroll
    for (int n = 0; n < 4; ++n) { bcur[n][0] = bpre[n][0]; bcur[n][1] = bpre[n][1]; }
    if (has_next) {
      int s1 = s + 1;
      int dy = s1 / 7, dx = s1 % 7;
      const __bf16* pin = prow + (dy*WP + dx)*CCH;
#pragma unroll
      for (int n = 0; n < 4; ++n)
#pragma unroll
        for (int kc = 0; kc < 2; ++kc)
          bpre[n][kc] = *reinterpret_cast<const bf16x8*>(pin + (n*16)*CCH + kc*32);
    }
#pragma unroll
    for (int kc = 0; kc < 2; ++kc)
#pragma unroll
      for (int m = 0; m < 2; ++m)
#pragma unroll
        for (int n = 0; n < 4; ++n)
          acc[m][n] = __builtin_amdgcn_mfma_f32_16x16x32_bf16(afr[m][kc], bcur[n][kc], acc[m][n], 0, 0, 0);
    if (has_next)
      *reinterpret_cast<bf16x8*>(&wlds[(s+1) & 1][sdst]) = wv;
  }
  // epilogue: C/D layout col=l16 (pixel), row=quad*4+r (kout within tile)
#pragma unroll
  for (int n = 0; n < 4; ++n) {
    int wpix = w0 + n*16 + l16;
    if (wpix < WW) {
#pragma unroll
      for (int m = 0; m < 2; ++m) {
#pragma unroll
        for (int r = 0; r < 4; ++r) {
          int kg = khalf*32 + m*16 + quad*4 + r;
          out[((size_t)(b*CCH + kg)*HH + h)*WW + wpix] = acc[m][n][r] + fb[kg];
        }
      }
    }
  }
}

extern "C" void kernel_launch(void* const* d_in, const int* in_sizes, int n_in,
                              void* d_out, int out_size, void* d_ws, size_t ws_size,
                              hipStream_t stream) {
  (void)in_sizes; (void)n_in; (void)out_size; (void)ws_size;
  const float* x   = (const float*)d_in[0];
  const float* psm = (const float*)d_in[1];
  // d_in[2] = record_len (unused by reference)
  const float* ptm = (const float*)d_in[3];
  const float* fw  = (const float*)d_in[4];
  const float* fb  = (const float*)d_in[5];
  float* out = (float*)d_out;
  char* ws = (char*)d_ws;
  float*        conf  = (float*)(ws + WS_CONF);
  float*        tau   = (float*)(ws + WS_TAU);
  int*          selp  = (int*)(ws + WS_SELP);
  int*          selk  = (int*)(ws + WS_SELK);
  __bf16*       wtp   = (__bf16*)(ws + WS_WTP);
  __bf16*       pad   = (__bf16*)(ws + WS_PAD);
  unsigned int* ghist = (unsigned int*)(ws + WS_GHIST);

  hipMemsetAsync(ws + WS_PAD, 0, PAD_BYTES + GHIST_BYTES, stream);  // pad + ghist contiguous
  conf_warp_kernel<<<dim3(3, HH, NN), 128, 0, stream>>>(psm, ptm, conf, ghist);
  pack_w_kernel<<<(CCH*CCH*49 + 255)/256, 256, 0, stream>>>(fw, wtp);
  topk_select_kernel<<<NN, 256, 0, stream>>>(ghist, selp, selk, tau, 0);
  scan_lo_kernel<<<dim3(16, NN), 256, 0, stream>>>(conf, selp, ghist);
  topk_select_kernel<<<NN, 256, 0, stream>>>(ghist, selp, selk, tau, 1);
  warp_avg_kernel<<<dim3(6, HH, NB), dim3(64, 4), 0, stream>>>(x, ptm, conf, tau, pad);
  conv_kernel<<<dim3(6, 25, 4), 256, 0, stream>>>(pad, wtp, fb, out);
}

// Round 4
// 452.045 us; speedup vs baseline: 1.1219x; 1.1219x over previous
//
#include <hip/hip_runtime.h>
#include <hip/hip_bf16.h>

#define HH 100
#define WW 352
#define NB 2
#define LL 5
#define NN 10
#define CCH 64
#define HW (HH*WW)
#define KTOP (HW/4)
#define HP (HH+6)
#define WP 390   // 6*64 + 6, covers conv reads for padded W tiles

typedef __bf16 bf16x8 __attribute__((ext_vector_type(8)));
typedef float f32x4 __attribute__((ext_vector_type(4)));

// ws layout (bytes), 16B aligned. Total 62,701,760 — assumes ws_size >= 63 MB.
#define WS_CONF  0u
#define WS_TAU   1408000u
#define WS_SELP  1408064u
#define WS_SELK  1408128u
#define WS_PART  1408192u
#define WS_WTP   1418432u
#define WS_PAD   1819840u
#define WS_GHI   12402880u
#define WS_GLO   15024320u
#define WS_XT    17645760u
#define PAD_BYTES   ((size_t)NB*HP*WP*CCH*2)      // 10,583,040
#define MEMSET_BYTES (10583040u + 2u*2621440u)    // pad + both hist regions

__device__ __forceinline__ void load_theta(const float* __restrict__ ptm, int b, int l, float th[6]) {
#pragma clang fp contract(off)
  const float* tb = ptm + ((b*LL + 0)*LL + l)*16;  // pairwise_t_matrix[b,0,l,:,:]
  th[0] = tb[0] * 1.0f;
  th[1] = tb[1] * (float)(100.0/352.0);
  th[2] = tb[3] * (float)(2.0/(2.0*0.4*352.0));
  th[3] = tb[4] * (float)(352.0/100.0);
  th[4] = tb[5] * 1.0f;
  th[5] = tb[7] * (float)(2.0/(2.0*0.4*100.0));
}

// --- Kernel 1: conf_w = bilinear-warp of sigmoid(max(psm)) + fused hi16 histogram ---
__global__ void conf_warp_kernel(const float* __restrict__ psm,
                                 const float* __restrict__ ptm,
                                 float* __restrict__ conf_w,
                                 unsigned int* __restrict__ ghist) {
#pragma clang fp contract(off)
  int w = blockIdx.x * 128 + threadIdx.x;
  int h = blockIdx.y;
  int n = blockIdx.z;
  if (w >= WW) return;
  int b = n / LL, l = n % LL;
  float th[6];
  load_theta(ptm, b, l, th);
  float gy = ((float)h + 0.5f) * (float)(2.0/100.0) - 1.0f;
  float gx = ((float)w + 0.5f) * (float)(2.0/352.0) - 1.0f;
  float sx = th[0]*gx + th[1]*gy + th[2];
  float sy = th[3]*gx + th[4]*gy + th[5];
  float px = (sx + 1.0f) * ((float)WW * 0.5f) - 0.5f;
  float py = (sy + 1.0f) * ((float)HH * 0.5f) - 0.5f;
  float x0 = floorf(px), y0 = floorf(py);
  float wx1 = px - x0, wx0 = 1.0f - wx1;
  float wy1 = py - y0, wy0 = 1.0f - wy1;
  const float* p0 = psm + (size_t)(n*2 + 0)*HW;
  const float* p1 = psm + (size_t)(n*2 + 1)*HW;
  float yy[2] = {y0, y0 + 1.0f};
  float xx[2] = {x0, x0 + 1.0f};
  float wgt[2][2] = {{wy0*wx0, wy0*wx1}, {wy1*wx0, wy1*wx1}};
  float out = 0.0f;
  for (int iy = 0; iy < 2; ++iy) {
    for (int ix = 0; ix < 2; ++ix) {
      float yv = yy[iy], xv = xx[ix];
      float yc = fminf(fmaxf(yv, 0.0f), (float)(HH-1));
      float xc = fminf(fmaxf(xv, 0.0f), (float)(WW-1));
      int yi = (int)yc, xi = (int)xc;
      int idx = yi*WW + xi;
      float m = fmaxf(p0[idx], p1[idx]);
      float v = 1.0f / (1.0f + expf(-m));
      bool valid = (yv >= 0.0f) && (yv <= (float)(HH-1)) && (xv >= 0.0f) && (xv <= (float)(WW-1));
      out += (valid ? v : 0.0f) * wgt[iy][ix];
    }
  }
  conf_w[(size_t)n*HW + h*WW + w] = out;
  // fused hi16 histogram, wave-aggregated (conf >= 0 -> bit order = float order)
  unsigned int bin = __float_as_uint(out) >> 16;
  int lane = threadIdx.x & 63;
  unsigned long long mask = __ballot(true);
  while (mask) {
    int srcl = (int)(__ffsll((long long)mask) - 1);
    unsigned int bsrc = (unsigned int)__shfl((int)bin, srcl);
    unsigned long long same = __ballot(bin == bsrc);
    if (lane == srcl)
      atomicAdd(&ghist[(size_t)n*65536 + bsrc], (unsigned int)__popcll(same & mask));
    mask &= ~same;
  }
}

// --- Kernel 2a: chunk sums of 65536-bin hist -> partial[n][256] (coalesced) ---
__global__ __launch_bounds__(256) void hist_sum_kernel(const unsigned int* __restrict__ gh,
                                                       unsigned int* __restrict__ partial) {
  __shared__ unsigned int ws[4];
  int n = blockIdx.y, j = blockIdx.x;
  int tid = threadIdx.x, lane = tid & 63, wid = tid >> 6;
  unsigned int v = gh[(size_t)n*65536 + j*256 + tid];
  for (int off = 32; off; off >>= 1) v += __shfl_down(v, off);
  if (lane == 0) ws[wid] = v;
  __syncthreads();
  if (tid == 0) partial[n*256 + j] = ws[0] + ws[1] + ws[2] + ws[3];
}

// inclusive scan over 256 threads (4 waves), thread order = descending bins
__device__ __forceinline__ unsigned int scan_incl(unsigned int v, int lane, int wid,
                                                  volatile unsigned int* wsum) {
  unsigned int inc = v;
  for (int off = 1; off < 64; off <<= 1) {
    unsigned int o = __shfl_up(inc, off);
    if (lane >= off) inc += o;
  }
  if (lane == 63) wsum[wid] = inc;
  __syncthreads();
  unsigned int wadd = 0;
  for (int w2 = 0; w2 < wid; ++w2) wadd += wsum[w2];
  return inc + wadd;
}

// --- Kernel 2b: two-level descending select. mode 0: hi16 -> selp/selk. mode 1: lo16 -> tau ---
__global__ __launch_bounds__(256) void select_kernel(const unsigned int* __restrict__ gh,
                                                     const unsigned int* __restrict__ partial,
                                                     int* __restrict__ selp,
                                                     int* __restrict__ selk,
                                                     float* __restrict__ tau, int mode) {
  __shared__ unsigned int wsA[4], wsB[4];
  __shared__ int s_chunk;
  __shared__ unsigned int s_krem;
  int n = blockIdx.x;
  int tid = threadIdx.x, lane = tid & 63, wid = tid >> 6;
  unsigned int k = (unsigned int)((mode == 0) ? KTOP : selk[n]);
  // level 1: chunks descending
  unsigned int c1 = partial[n*256 + (255 - tid)];
  unsigned int incl1 = scan_incl(c1, lane, wid, wsA);
  unsigned int excl1 = incl1 - c1;
  if (excl1 < k && incl1 >= k) { s_chunk = 255 - tid; s_krem = k - excl1; }
  __syncthreads();
  int ch = s_chunk;
  unsigned int k2 = s_krem;
  // level 2: bins within chunk, descending
  unsigned int c2 = gh[(size_t)n*65536 + ch*256 + (255 - tid)];
  unsigned int incl2 = scan_incl(c2, lane, wid, wsB);
  unsigned int excl2 = incl2 - c2;
  if (excl2 < k2 && incl2 >= k2) {
    int bin = ch*256 + (255 - tid);
    if (mode == 0) { selp[n] = bin; selk[n] = (int)(k2 - excl2); }
    else tau[n] = __uint_as_float(((unsigned int)selp[n] << 16) | (unsigned int)bin);
  }
}

// --- Kernel 2c: conditional rescan — lo16 histogram among elements matching hi16 prefix ---
__global__ void scan_lo_kernel(const float* __restrict__ conf_w,
                               const int* __restrict__ selp,
                               unsigned int* __restrict__ ghlo) {
  int n = blockIdx.y;
  unsigned int hi = (unsigned int)selp[n];
  const float4* src = (const float4*)(conf_w + (size_t)n*HW);
  unsigned int* gh = ghlo + (size_t)n*65536;
  for (int i = blockIdx.x*256 + threadIdx.x; i < HW/4; i += 16*256) {
    float4 v = src[i];
    unsigned int u0 = __float_as_uint(v.x);
    unsigned int u1 = __float_as_uint(v.y);
    unsigned int u2 = __float_as_uint(v.z);
    unsigned int u3 = __float_as_uint(v.w);
    if ((u0 >> 16) == hi) atomicAdd(&gh[u0 & 0xFFFFu], 1u);
    if ((u1 >> 16) == hi) atomicAdd(&gh[u1 & 0xFFFFu], 1u);
    if ((u2 >> 16) == hi) atomicAdd(&gh[u2 & 0xFFFFu], 1u);
    if ((u3 >> 16) == hi) atomicAdd(&gh[u3 & 0xFFFFu], 1u);
  }
}

// --- Kernel 3: weights fuse_w[k][c][dy][dx] -> wtp[(dy*7+dx)*64 + k][c] bf16 ---
__global__ void pack_w_kernel(const float* __restrict__ fw, __bf16* __restrict__ wtp) {
  int idx = blockIdx.x*256 + threadIdx.x;
  if (idx >= CCH*CCH*49) return;
  int c = idx & 63;
  int k = (idx >> 6) & 63;
  int dydx = idx >> 12;
  wtp[((size_t)dydx*CCH + k)*CCH + c] = (__bf16)fw[((size_t)k*CCH + c)*49 + dydx];
}

// --- Kernel 3b: x (N,C,H,W) f32 -> xT (N,H*W,C) bf16 via LDS transpose ---
__global__ __launch_bounds__(256) void repack_x_kernel(const float* __restrict__ x,
                                                       __bf16* __restrict__ xT) {
  __shared__ float tile[64][65];
  int n = blockIdx.y;
  int px0 = blockIdx.x * 64;
  int tid = threadIdx.x;
  int pxl = tid & 63;
  int c0 = tid >> 6;       // 0..3
  const float* xs = x + (size_t)n*CCH*HW + px0 + pxl;
#pragma unroll
  for (int i = 0; i < 16; ++i) {
    int c = c0 + i*4;
    tile[c][pxl] = xs[(size_t)c*HW];
  }
  __syncthreads();
  int px2 = tid >> 2;            // 0..63
  int cc0 = (tid & 3) * 16;      // 0,16,32,48
  __bf16 vv[16];
#pragma unroll
  for (int j = 0; j < 16; ++j) vv[j] = (__bf16)tile[cc0 + j][px2];
  __bf16* dst = xT + ((size_t)n*HW + px0 + px2)*CCH + cc0;
  *reinterpret_cast<bf16x8*>(dst)     = *reinterpret_cast<bf16x8*>(&vv[0]);
  *reinterpret_cast<bf16x8*>(dst + 8) = *reinterpret_cast<bf16x8*>(&vv[8]);
}

// --- Kernel 4: fused warp + mask + mean over L; NHWC bf16 gather, one thread = one px, all 64 ch ---
__global__ __launch_bounds__(256) void warp_avg_kernel(
    const __bf16* __restrict__ xT, const float* __restrict__ ptm,
    const float* __restrict__ conf_w, const float* __restrict__ tau,
    __bf16* __restrict__ pad) {
  int px = blockIdx.x*256 + threadIdx.x;  // 0..70399
  int b = (px >= HW) ? 1 : 0;
  int rem = px - b*HW;
  int h = rem / WW;
  int w = rem - h*WW;
  float acc[64];
#pragma unroll
  for (int i = 0; i < 64; ++i) acc[i] = 0.0f;
  float gy = ((float)h + 0.5f) * (float)(2.0/100.0) - 1.0f;
  float gx = ((float)w + 0.5f) * (float)(2.0/352.0) - 1.0f;
  for (int l = 0; l < LL; ++l) {
    int n = b*LL + l;
    if (l != 0 && !(conf_w[(size_t)n*HW + rem] >= tau[n])) continue;
    float th[6];
    load_theta(ptm, b, l, th);
    float sx = th[0]*gx + th[1]*gy + th[2];
    float sy = th[3]*gx + th[4]*gy + th[5];
    float fpx = (sx + 1.0f) * ((float)WW*0.5f) - 0.5f;
    float fpy = (sy + 1.0f) * ((float)HH*0.5f) - 0.5f;
    float x0 = floorf(fpx), y0 = floorf(fpy);
    float wx1 = fpx - x0, wx0 = 1.0f - wx1;
    float wy1 = fpy - y0, wy0 = 1.0f - wy1;
    float y1 = y0 + 1.0f, x1 = x0 + 1.0f;
    bool vy0 = (y0 >= 0.0f) && (y0 <= (float)(HH-1));
    bool vy1 = (y1 >= 0.0f) && (y1 <= (float)(HH-1));
    bool vx0 = (x0 >= 0.0f) && (x0 <= (float)(WW-1));
    bool vx1 = (x1 >= 0.0f) && (x1 <= (float)(WW-1));
    int yi0 = (int)fminf(fmaxf(y0, 0.0f), (float)(HH-1));
    int yi1 = (int)fminf(fmaxf(y1, 0.0f), (float)(HH-1));
    int xi0 = (int)fminf(fmaxf(x0, 0.0f), (float)(WW-1));
    int xi1 = (int)fminf(fmaxf(x1, 0.0f), (float)(WW-1));
    float wgt[4] = { wy0*wx0 * ((vy0 && vx0) ? 1.0f : 0.0f),
                     wy0*wx1 * ((vy0 && vx1) ? 1.0f : 0.0f),
                     wy1*wx0 * ((vy1 && vx0) ? 1.0f : 0.0f),
                     wy1*wx1 * ((vy1 && vx1) ? 1.0f : 0.0f) };
    int off[4] = { yi0*WW + xi0, yi0*WW + xi1, yi1*WW + xi0, yi1*WW + xi1 };
#pragma unroll
    for (int t4 = 0; t4 < 4; ++t4) {
      if (wgt[t4] == 0.0f) continue;
      float wt = wgt[t4];
      const __bf16* src = xT + ((size_t)n*HW + off[t4])*CCH;
#pragma unroll
      for (int ch = 0; ch < 8; ++ch) {
        bf16x8 v = *reinterpret_cast<const bf16x8*>(src + ch*8);
#pragma unroll
        for (int e = 0; e < 8; ++e) acc[ch*8 + e] += wt * (float)v[e];
      }
    }
  }
  __bf16* dst = pad + (((size_t)b*HP + (h+3))*WP + (w+3))*CCH;
#pragma unroll
  for (int ch = 0; ch < 8; ++ch) {
    bf16x8 o;
#pragma unroll
    for (int e = 0; e < 8; ++e) o[e] = (__bf16)(acc[ch*8 + e]*0.2f);
    *reinterpret_cast<bf16x8*>(dst + ch*8) = o;
  }
}

// --- Kernel 5: 7x7 conv implicit GEMM. Block: 4 waves x (1 row, 64 px, 64 kout).
// Per-dy weight staging into swizzled LDS (57 KB); B from global/L1, pipelined over dx.
// m-reuse=4, n-reuse=4: fragment demand ~105 B/cyc vs LDS 85 + L1 supply. ---
__global__ __launch_bounds__(256, 2) void conv_kernel(
    const __bf16* __restrict__ pad, const __bf16* __restrict__ wtp,
    const float* __restrict__ fb, float* __restrict__ out) {
  __shared__ __align__(16) __bf16 wlds[7*64*64];  // 57344 B: [dx][k][c], chunk-rotated
  int tid = threadIdx.x;
  int wave = tid >> 6, lane = tid & 63;
  int quad = lane >> 4, l16 = lane & 15;
  int b = blockIdx.z;
  int h = blockIdx.y*4 + wave;
  int w0 = blockIdx.x*64;
  f32x4 acc[4][4];
#pragma unroll
  for (int m = 0; m < 4; ++m)
#pragma unroll
    for (int n = 0; n < 4; ++n) acc[m][n] = (f32x4){0.f,0.f,0.f,0.f};
  const __bf16* prow = pad + (((size_t)b*HP + h)*WP + w0 + l16)*CCH + quad*8;
  // staging constants: lane covers LDS (row r, chunk jc) within a 1KB region
  int r8 = lane >> 3, jc = lane & 7;
  int jcr = (jc - r8) & 7;
  // A-frag chunk indices (swizzle: global chunk j of row R stored at (j+R)&7; R&7 == k&7 == l16&7... uses k)
  int cj0 = (quad + l16) & 7;        // kc=0
  int cj1 = (quad + 4 + l16) & 7;    // kc=1
#pragma unroll 1
  for (int dy = 0; dy < 7; ++dy) {
    if (dy) __syncthreads();         // all reads of previous dy done
    // stage weights for dy: 448 rows x 128B, rotate-swizzled per row
    const __bf16* wdy = wtp + dy*28672;
#pragma unroll
    for (int j = 0; j < 14; ++j) {
      int q = wave*14 + j;           // 1KB region id
      int R = q*8 + r8;              // global row (dx*64 + k)
      int jp = (jcr - q*8) & 7;      // global chunk held at this LDS slot
      bf16x8 v = *reinterpret_cast<const bf16x8*>(wdy + R*64 + jp*8);
      *reinterpret_cast<bf16x8*>(&wlds[q*512 + r8*64 + jc*8]) = v;
    }
    // prefetch B for dx=0
    bf16x8 bfr[2][4][2];
#pragma unroll
    for (int n = 0; n < 4; ++n)
#pragma unroll
      for (int kc = 0; kc < 2; ++kc)
        bfr[0][n][kc] = *reinterpret_cast<const bf16x8*>(prow + ((size_t)dy*WP + n*16)*CCH + kc*32);
    __syncthreads();                 // staging visible
#pragma unroll
    for (int dx = 0; dx < 7; ++dx) {
      int cur = dx & 1, nxt = cur ^ 1;
      if (dx < 6) {
#pragma unroll
        for (int n = 0; n < 4; ++n)
#pragma unroll
          for (int kc = 0; kc < 2; ++kc)
            bfr[nxt][n][kc] = *reinterpret_cast<const bf16x8*>(prow + ((size_t)dy*WP + dx + 1 + n*16)*CCH + kc*32);
      }
      bf16x8 af[4][2];
#pragma unroll
      for (int m = 0; m < 4; ++m) {
        af[m][0] = *reinterpret_cast<const bf16x8*>(&wlds[(dx*64 + m*16 + l16)*64 + cj0*8]);
        af[m][1] = *reinterpret_cast<const bf16x8*>(&wlds[(dx*64 + m*16 + l16)*64 + cj1*8]);
      }
#pragma unroll
      for (int kc = 0; kc < 2; ++kc)
#pragma unroll
        for (int m = 0; m < 4; ++m)
#pragma unroll
          for (int n = 0; n < 4; ++n)
            acc[m][n] = __builtin_amdgcn_mfma_f32_16x16x32_bf16(af[m][kc], bfr[cur][n][kc], acc[m][n], 0, 0, 0);
    }
  }
  // epilogue: C/D col = l16 (pixel), row = quad*4 + r (kout within 16-tile)
#pragma unroll
  for (int n = 0; n < 4; ++n) {
    int wpix = w0 + n*16 + l16;
    if (wpix < WW) {
#pragma unroll
      for (int m = 0; m < 4; ++m) {
#pragma unroll
        for (int rr = 0; rr < 4; ++rr) {
          int kg = m*16 + quad*4 + rr;
          out[((size_t)(b*CCH + kg)*HH + h)*WW + wpix] = acc[m][n][rr] + fb[kg];
        }
      }
    }
  }
}

extern "C" void kernel_launch(void* const* d_in, const int* in_sizes, int n_in,
                              void* d_out, int out_size, void* d_ws, size_t ws_size,
                              hipStream_t stream) {
  (void)in_sizes; (void)n_in; (void)out_size; (void)ws_size;
  const float* x   = (const float*)d_in[0];
  const float* psm = (const float*)d_in[1];
  // d_in[2] = record_len (unused by reference)
  const float* ptm = (const float*)d_in[3];
  const float* fw  = (const float*)d_in[4];
  const float* fb  = (const float*)d_in[5];
  float* out = (float*)d_out;
  char* ws = (char*)d_ws;
  float*        conf  = (float*)(ws + WS_CONF);
  float*        tau   = (float*)(ws + WS_TAU);
  int*          selp  = (int*)(ws + WS_SELP);
  int*          selk  = (int*)(ws + WS_SELK);
  unsigned int* part  = (unsigned int*)(ws + WS_PART);
  __bf16*       wtp   = (__bf16*)(ws + WS_WTP);
  __bf16*       pad   = (__bf16*)(ws + WS_PAD);
  unsigned int* ghi   = (unsigned int*)(ws + WS_GHI);
  unsigned int* glo   = (unsigned int*)(ws + WS_GLO);
  __bf16*       xT    = (__bf16*)(ws + WS_XT);

  hipMemsetAsync(ws + WS_PAD, 0, MEMSET_BYTES, stream);  // pad halo + both hist regions
  conf_warp_kernel<<<dim3(3, HH, NN), 128, 0, stream>>>(psm, ptm, conf, ghi);
  pack_w_kernel<<<(CCH*CCH*49 + 255)/256, 256, 0, stream>>>(fw, wtp);
  repack_x_kernel<<<dim3(HW/64, NN), 256, 0, stream>>>(x, xT);
  hist_sum_kernel<<<dim3(256, NN), 256, 0, stream>>>(ghi, part);
  select_kernel<<<NN, 256, 0, stream>>>(ghi, part, selp, selk, tau, 0);
  scan_lo_kernel<<<dim3(16, NN), 256, 0, stream>>>(conf, selp, glo);
  hist_sum_kernel<<<dim3(256, NN), 256, 0, stream>>>(glo, part);
  select_kernel<<<NN, 256, 0, stream>>>(glo, part, selp, selk, tau, 1);
  warp_avg_kernel<<<dim3(NB*HW/256), 256, 0, stream>>>(xT, ptm, conf, tau, pad);
  conv_kernel<<<dim3(6, 25, NB), 256, 0, stream>>>(pad, wtp, fb, out);
}

// Round 5
// 353.034 us; speedup vs baseline: 1.4365x; 1.2805x over previous
//
#include <hip/hip_runtime.h>
#include <hip/hip_bf16.h>

#define HH 100
#define WW 352
#define NB 2
#define LL 5
#define NN 10
#define CCH 64
#define HW (HH*WW)
#define KTOP (HW/4)
#define HP (HH+6)
#define WP 390   // 6*64 + 6, covers conv reads for padded W tiles

typedef __bf16 bf16x8 __attribute__((ext_vector_type(8)));
typedef float f32x4 __attribute__((ext_vector_type(4)));

// ws layout (bytes), 16B aligned
#define WS_CONF  0u
#define WS_TAU   1408000u
#define WS_WTP   1408064u
#define WS_PAD   1809472u
#define WS_XT    12392512u
#define PAD_BYTES ((size_t)NB*HP*WP*CCH*2)      // 10,583,040

__device__ __forceinline__ void load_theta(const float* __restrict__ ptm, int b, int l, float th[6]) {
#pragma clang fp contract(off)
  const float* tb = ptm + ((b*LL + 0)*LL + l)*16;  // pairwise_t_matrix[b,0,l,:,:]
  th[0] = tb[0] * 1.0f;
  th[1] = tb[1] * (float)(100.0/352.0);
  th[2] = tb[3] * (float)(2.0/(2.0*0.4*352.0));
  th[3] = tb[4] * (float)(352.0/100.0);
  th[4] = tb[5] * 1.0f;
  th[5] = tb[7] * (float)(2.0/(2.0*0.4*100.0));
}

// --- Kernel 1: conf_w = bilinear-warp of sigmoid(max(psm[n,0],psm[n,1])) ---
__global__ void conf_warp_kernel(const float* __restrict__ psm,
                                 const float* __restrict__ ptm,
                                 float* __restrict__ conf_w) {
#pragma clang fp contract(off)
  int w = blockIdx.x * 128 + threadIdx.x;
  int h = blockIdx.y;
  int n = blockIdx.z;
  if (w >= WW) return;
  int b = n / LL, l = n % LL;
  float th[6];
  load_theta(ptm, b, l, th);
  float gy = ((float)h + 0.5f) * (float)(2.0/100.0) - 1.0f;
  float gx = ((float)w + 0.5f) * (float)(2.0/352.0) - 1.0f;
  float sx = th[0]*gx + th[1]*gy + th[2];
  float sy = th[3]*gx + th[4]*gy + th[5];
  float px = (sx + 1.0f) * ((float)WW * 0.5f) - 0.5f;
  float py = (sy + 1.0f) * ((float)HH * 0.5f) - 0.5f;
  float x0 = floorf(px), y0 = floorf(py);
  float wx1 = px - x0, wx0 = 1.0f - wx1;
  float wy1 = py - y0, wy0 = 1.0f - wy1;
  const float* p0 = psm + (size_t)(n*2 + 0)*HW;
  const float* p1 = psm + (size_t)(n*2 + 1)*HW;
  float yy[2] = {y0, y0 + 1.0f};
  float xx[2] = {x0, x0 + 1.0f};
  float wgt[2][2] = {{wy0*wx0, wy0*wx1}, {wy1*wx0, wy1*wx1}};
  float out = 0.0f;
  for (int iy = 0; iy < 2; ++iy) {
    for (int ix = 0; ix < 2; ++ix) {
      float yv = yy[iy], xv = xx[ix];
      float yc = fminf(fmaxf(yv, 0.0f), (float)(HH-1));
      float xc = fminf(fmaxf(xv, 0.0f), (float)(WW-1));
      int yi = (int)yc, xi = (int)xc;
      int idx = yi*WW + xi;
      float m = fmaxf(p0[idx], p1[idx]);
      float v = 1.0f / (1.0f + expf(-m));
      bool valid = (yv >= 0.0f) && (yv <= (float)(HH-1)) && (xv >= 0.0f) && (xv <= (float)(WW-1));
      out += (valid ? v : 0.0f) * wgt[iy][ix];
    }
  }
  conf_w[(size_t)n*HW + h*WW + w] = out;
}

// inclusive block scan over 256 threads (thread order = descending bins)
__device__ __forceinline__ unsigned int scan_incl(unsigned int v, int lane, int wid,
                                                  volatile unsigned int* wsum) {
  unsigned int inc = v;
  for (int off = 1; off < 64; off <<= 1) {
    unsigned int o = __shfl_up(inc, off);
    if (lane >= off) inc += o;
  }
  if (lane == 63) wsum[wid] = inc;
  __syncthreads();
  unsigned int wadd = 0;
  for (int w2 = 0; w2 < wid; ++w2) wadd += wsum[w2];
  return inc + wadd;
}

// --- Kernel 2: exact K-th largest per image, 3-round (14/14/4-bit) LDS radix select ---
// One block per image; conf re-read from L2/L3 each round (137 KB). conf >= 0 so
// float order == unsigned bit order.
__global__ __launch_bounds__(256) void topk_kernel(const float* __restrict__ conf_w,
                                                   float* __restrict__ tau) {
  __shared__ unsigned int hist[16384];
  __shared__ unsigned int wsum[4];
  __shared__ unsigned int s_pref, s_mask, s_k;
  int n = blockIdx.x;
  int tid = threadIdx.x, lane = tid & 63, wid = tid >> 6;
  const float4* src = (const float4*)(conf_w + (size_t)n*HW);
  if (tid == 0) { s_pref = 0u; s_mask = 0u; s_k = KTOP; }
  __syncthreads();
  const int shifts[3] = {18, 4, 0};
  const int widths[3] = {14, 14, 4};
  for (int r = 0; r < 3; ++r) {
    int shift = shifts[r];
    int nbins = 1 << widths[r];
    unsigned int fmask = (unsigned int)(nbins - 1);
    for (int i = tid; i < nbins; i += 256) hist[i] = 0u;
    __syncthreads();
    unsigned int maskhi = s_mask, pref = s_pref, k = s_k;
    for (int i = tid; i < HW/4; i += 256) {
      float4 v = src[i];
      unsigned int u0 = __float_as_uint(v.x);
      unsigned int u1 = __float_as_uint(v.y);
      unsigned int u2 = __float_as_uint(v.z);
      unsigned int u3 = __float_as_uint(v.w);
      if ((u0 & maskhi) == pref) atomicAdd(&hist[(u0 >> shift) & fmask], 1u);
      if ((u1 & maskhi) == pref) atomicAdd(&hist[(u1 >> shift) & fmask], 1u);
      if ((u2 & maskhi) == pref) atomicAdd(&hist[(u2 >> shift) & fmask], 1u);
      if ((u3 & maskhi) == pref) atomicAdd(&hist[(u3 >> shift) & fmask], 1u);
    }
    __syncthreads();
    // descending select over nbins
    int C = nbins >> 8; if (C == 0) C = 1;
    int active = (C * 256 > nbins) ? nbins : 256;
    int top = nbins - 1 - tid*C;
    unsigned int csum = 0u;
    if (tid < active)
      for (int i = 0; i < C; ++i) csum += hist[top - i];
    unsigned int incl = scan_incl(csum, lane, wid, wsum);
    unsigned int excl = incl - csum;
    if (tid < active && excl < k && incl >= k) {
      unsigned int run = excl;
      for (int i = 0; i < C; ++i) {
        unsigned int c = hist[top - i];
        if (run + c >= k) {
          unsigned int bin = (unsigned int)(top - i);
          s_pref = pref | (bin << shift);
          s_mask = maskhi | (fmask << shift);
          s_k = k - run;
          break;
        }
        run += c;
      }
    }
    __syncthreads();
  }
  if (tid == 0) tau[n] = __uint_as_float(s_pref);
}

// --- Kernel 3: weights fuse_w[k][c][dy][dx] -> wtp[(dy*7+dx)*64 + k][c] bf16 ---
__global__ void pack_w_kernel(const float* __restrict__ fw, __bf16* __restrict__ wtp) {
  int idx = blockIdx.x*256 + threadIdx.x;
  if (idx >= CCH*CCH*49) return;
  int c = idx & 63;
  int k = (idx >> 6) & 63;
  int dydx = idx >> 12;
  wtp[((size_t)dydx*CCH + k)*CCH + c] = (__bf16)fw[((size_t)k*CCH + c)*49 + dydx];
}

// --- Kernel 3b: x (N,C,H,W) f32 -> xT (N,H*W,C) bf16 via LDS transpose ---
__global__ __launch_bounds__(256) void repack_x_kernel(const float* __restrict__ x,
                                                       __bf16* __restrict__ xT) {
  __shared__ float tile[64][65];
  int n = blockIdx.y;
  int px0 = blockIdx.x * 64;
  int tid = threadIdx.x;
  int pxl = tid & 63;
  int c0 = tid >> 6;       // 0..3
  const float* xs = x + (size_t)n*CCH*HW + px0 + pxl;
#pragma unroll
  for (int i = 0; i < 16; ++i) {
    int c = c0 + i*4;
    tile[c][pxl] = xs[(size_t)c*HW];
  }
  __syncthreads();
  int px2 = tid >> 2;            // 0..63
  int cc0 = (tid & 3) * 16;      // 0,16,32,48
  __bf16 vv[16];
#pragma unroll
  for (int j = 0; j < 16; ++j) vv[j] = (__bf16)tile[cc0 + j][px2];
  __bf16* dst = xT + ((size_t)n*HW + px0 + px2)*CCH + cc0;
  *reinterpret_cast<bf16x8*>(dst)     = *reinterpret_cast<bf16x8*>(&vv[0]);
  *reinterpret_cast<bf16x8*>(dst + 8) = *reinterpret_cast<bf16x8*>(&vv[8]);
}

// --- Kernel 4: fused warp + mask + mean over L; NHWC bf16 gather, one thread = one px ---
__global__ __launch_bounds__(256) void warp_avg_kernel(
    const __bf16* __restrict__ xT, const float* __restrict__ ptm,
    const float* __restrict__ conf_w, const float* __restrict__ tau,
    __bf16* __restrict__ pad) {
  int px = blockIdx.x*256 + threadIdx.x;  // 0..70399
  int b = (px >= HW) ? 1 : 0;
  int rem = px - b*HW;
  int h = rem / WW;
  int w = rem - h*WW;
  float acc[64];
#pragma unroll
  for (int i = 0; i < 64; ++i) acc[i] = 0.0f;
  float gy = ((float)h + 0.5f) * (float)(2.0/100.0) - 1.0f;
  float gx = ((float)w + 0.5f) * (float)(2.0/352.0) - 1.0f;
  for (int l = 0; l < LL; ++l) {
    int n = b*LL + l;
    if (l != 0 && !(conf_w[(size_t)n*HW + rem] >= tau[n])) continue;
    float th[6];
    load_theta(ptm, b, l, th);
    float sx = th[0]*gx + th[1]*gy + th[2];
    float sy = th[3]*gx + th[4]*gy + th[5];
    float fpx = (sx + 1.0f) * ((float)WW*0.5f) - 0.5f;
    float fpy = (sy + 1.0f) * ((float)HH*0.5f) - 0.5f;
    float x0 = floorf(fpx), y0 = floorf(fpy);
    float wx1 = fpx - x0, wx0 = 1.0f - wx1;
    float wy1 = fpy - y0, wy0 = 1.0f - wy1;
    float y1 = y0 + 1.0f, x1 = x0 + 1.0f;
    bool vy0 = (y0 >= 0.0f) && (y0 <= (float)(HH-1));
    bool vy1 = (y1 >= 0.0f) && (y1 <= (float)(HH-1));
    bool vx0 = (x0 >= 0.0f) && (x0 <= (float)(WW-1));
    bool vx1 = (x1 >= 0.0f) && (x1 <= (float)(WW-1));
    int yi0 = (int)fminf(fmaxf(y0, 0.0f), (float)(HH-1));
    int yi1 = (int)fminf(fmaxf(y1, 0.0f), (float)(HH-1));
    int xi0 = (int)fminf(fmaxf(x0, 0.0f), (float)(WW-1));
    int xi1 = (int)fminf(fmaxf(x1, 0.0f), (float)(WW-1));
    float wgt[4] = { wy0*wx0 * ((vy0 && vx0) ? 1.0f : 0.0f),
                     wy0*wx1 * ((vy0 && vx1) ? 1.0f : 0.0f),
                     wy1*wx0 * ((vy1 && vx0) ? 1.0f : 0.0f),
                     wy1*wx1 * ((vy1 && vx1) ? 1.0f : 0.0f) };
    int off[4] = { yi0*WW + xi0, yi0*WW + xi1, yi1*WW + xi0, yi1*WW + xi1 };
#pragma unroll
    for (int t4 = 0; t4 < 4; ++t4) {
      if (wgt[t4] == 0.0f) continue;
      float wt = wgt[t4];
      const __bf16* src = xT + ((size_t)n*HW + off[t4])*CCH;
#pragma unroll
      for (int ch = 0; ch < 8; ++ch) {
        bf16x8 v = *reinterpret_cast<const bf16x8*>(src + ch*8);
#pragma unroll
        for (int e = 0; e < 8; ++e) acc[ch*8 + e] += wt * (float)v[e];
      }
    }
  }
  __bf16* dst = pad + (((size_t)b*HP + (h+3))*WP + (w+3))*CCH;
#pragma unroll
  for (int ch = 0; ch < 8; ++ch) {
    bf16x8 o;
#pragma unroll
    for (int e = 0; e < 8; ++e) o[e] = (__bf16)(acc[ch*8 + e]*0.2f);
    *reinterpret_cast<bf16x8*>(dst + ch*8) = o;
  }
}

// --- Kernel 5: 7x7 conv implicit GEMM. Block: 4 waves x (1 row, 64 px, 64 kout). ---
__global__ __launch_bounds__(256, 2) void conv_kernel(
    const __bf16* __restrict__ pad, const __bf16* __restrict__ wtp,
    const float* __restrict__ fb, float* __restrict__ out) {
  __shared__ __align__(16) __bf16 wlds[7*64*64];  // 57344 B: [dx][k][c], chunk-rotated
  int tid = threadIdx.x;
  int wave = tid >> 6, lane = tid & 63;
  int quad = lane >> 4, l16 = lane & 15;
  int b = blockIdx.z;
  int h = blockIdx.y*4 + wave;
  int w0 = blockIdx.x*64;
  f32x4 acc[4][4];
#pragma unroll
  for (int m = 0; m < 4; ++m)
#pragma unroll
    for (int n = 0; n < 4; ++n) acc[m][n] = (f32x4){0.f,0.f,0.f,0.f};
  const __bf16* prow = pad + (((size_t)b*HP + h)*WP + w0 + l16)*CCH + quad*8;
  int r8 = lane >> 3, jc = lane & 7;
  int jcr = (jc - r8) & 7;
  int cj0 = (quad + l16) & 7;        // kc=0
  int cj1 = (quad + 4 + l16) & 7;    // kc=1
#pragma unroll 1
  for (int dy = 0; dy < 7; ++dy) {
    if (dy) __syncthreads();
    const __bf16* wdy = wtp + dy*28672;
#pragma unroll
    for (int j = 0; j < 14; ++j) {
      int q = wave*14 + j;
      int R = q*8 + r8;
      int jp = (jcr - q*8) & 7;
      bf16x8 v = *reinterpret_cast<const bf16x8*>(wdy + R*64 + jp*8);
      *reinterpret_cast<bf16x8*>(&wlds[q*512 + r8*64 + jc*8]) = v;
    }
    bf16x8 bfr[2][4][2];
#pragma unroll
    for (int n = 0; n < 4; ++n)
#pragma unroll
      for (int kc = 0; kc < 2; ++kc)
        bfr[0][n][kc] = *reinterpret_cast<const bf16x8*>(prow + ((size_t)dy*WP + n*16)*CCH + kc*32);
    __syncthreads();
#pragma unroll
    for (int dx = 0; dx < 7; ++dx) {
      int cur = dx & 1, nxt = cur ^ 1;
      if (dx < 6) {
#pragma unroll
        for (int n = 0; n < 4; ++n)
#pragma unroll
          for (int kc = 0; kc < 2; ++kc)
            bfr[nxt][n][kc] = *reinterpret_cast<const bf16x8*>(prow + ((size_t)dy*WP + dx + 1 + n*16)*CCH + kc*32);
      }
      bf16x8 af[4][2];
#pragma unroll
      for (int m = 0; m < 4; ++m) {
        af[m][0] = *reinterpret_cast<const bf16x8*>(&wlds[(dx*64 + m*16 + l16)*64 + cj0*8]);
        af[m][1] = *reinterpret_cast<const bf16x8*>(&wlds[(dx*64 + m*16 + l16)*64 + cj1*8]);
      }
#pragma unroll
      for (int kc = 0; kc < 2; ++kc)
#pragma unroll
        for (int m = 0; m < 4; ++m)
#pragma unroll
          for (int n = 0; n < 4; ++n)
            acc[m][n] = __builtin_amdgcn_mfma_f32_16x16x32_bf16(af[m][kc], bfr[cur][n][kc], acc[m][n], 0, 0, 0);
    }
  }
#pragma unroll
  for (int n = 0; n < 4; ++n) {
    int wpix = w0 + n*16 + l16;
    if (wpix < WW) {
#pragma unroll
      for (int m = 0; m < 4; ++m) {
#pragma unroll
        for (int rr = 0; rr < 4; ++rr) {
          int kg = m*16 + quad*4 + rr;
          out[((size_t)(b*CCH + kg)*HH + h)*WW + wpix] = acc[m][n][rr] + fb[kg];
        }
      }
    }
  }
}

extern "C" void kernel_launch(void* const* d_in, const int* in_sizes, int n_in,
                              void* d_out, int out_size, void* d_ws, size_t ws_size,
                              hipStream_t stream) {
  (void)in_sizes; (void)n_in; (void)out_size; (void)ws_size;
  const float* x   = (const float*)d_in[0];
  const float* psm = (const float*)d_in[1];
  // d_in[2] = record_len (unused by reference)
  const float* ptm = (const float*)d_in[3];
  const float* fw  = (const float*)d_in[4];
  const float* fb  = (const float*)d_in[5];
  float* out = (float*)d_out;
  char* ws = (char*)d_ws;
  float*  conf = (float*)(ws + WS_CONF);
  float*  tau  = (float*)(ws + WS_TAU);
  __bf16* wtp  = (__bf16*)(ws + WS_WTP);
  __bf16* pad  = (__bf16*)(ws + WS_PAD);
  __bf16* xT   = (__bf16*)(ws + WS_XT);

  hipMemsetAsync(pad, 0, PAD_BYTES, stream);
  conf_warp_kernel<<<dim3(3, HH, NN), 128, 0, stream>>>(psm, ptm, conf);
  pack_w_kernel<<<(CCH*CCH*49 + 255)/256, 256, 0, stream>>>(fw, wtp);
  repack_x_kernel<<<dim3(HW/64, NN), 256, 0, stream>>>(x, xT);
  topk_kernel<<<NN, 256, 0, stream>>>(conf, tau);
  warp_avg_kernel<<<dim3(NB*HW/256), 256, 0, stream>>>(xT, ptm, conf, tau, pad);
  conv_kernel<<<dim3(6, 25, NB), 256, 0, stream>>>(pad, wtp, fb, out);
}